// Round 3
// baseline (2231.179 us; speedup 1.0000x reference)
//
#include <hip/hip_runtime.h>

#define T_STEPS 2048

typedef float f2 __attribute__((ext_vector_type(2)));

__device__ __forceinline__ float fast_rcp(float x) { return __builtin_amdgcn_rcpf(x); }

// sigmoid family: sigmoid(x): zm=1,sm=1,sa=0 ; tanh(x)=2*sigmoid(2x)-1: zm=2,sm=2,sa=-1
__device__ __forceinline__ float gate_act(float x, float zm, float sm, float sa) {
    float e = __expf(-x * zm);
    return fmaf(fast_rcp(1.0f + e), sm, sa);
}

__device__ __forceinline__ float tanh_f(float c) {
    float e = __expf(-2.0f * c);
    return fmaf(2.0f, fast_rcp(1.0f + e), -1.0f);
}

__device__ __forceinline__ void loadx4(float (&dst)[4], const float* __restrict__ x_r,
                                       const float* __restrict__ x_t,
                                       size_t xrb, size_t xtb, int l) {
#pragma unroll
    for (int u = 0; u < 4; ++u) {
        int v = l + 16 * u;
        dst[u] = (v < 47) ? x_r[xrb + v] : ((v < 49) ? x_t[xtb + (v - 47)] : 0.0f);
    }
}

__global__ __launch_bounds__(448) void adrnn_fused(
    const float* __restrict__ x_r, const float* __restrict__ x_t,
    const float* __restrict__ rWih0, const float* __restrict__ rWhh0,
    const float* __restrict__ rbih0, const float* __restrict__ rbhh0,
    const float* __restrict__ rWih1, const float* __restrict__ rWhh1,
    const float* __restrict__ rbih1, const float* __restrict__ rbhh1,
    const float* __restrict__ tWih0, const float* __restrict__ tWhh0,
    const float* __restrict__ tbih0, const float* __restrict__ tbhh0,
    const float* __restrict__ tWih1, const float* __restrict__ tWhh1,
    const float* __restrict__ tbih1, const float* __restrict__ tbhh1,
    float* __restrict__ r_out, float* __restrict__ t_out)
{
    // ping-pong input vectors; iter i reads buf[i&1], writes buf[(i+1)&1]
    __shared__ __align__(16) float in0[2][96];   // [x_r(47)|x_t(2)|hr0(47)]
    __shared__ __align__(16) float in1[2][96];   // [hr0(47)|pad|hr1(47)|pad]
    __shared__ __align__(16) float ring[4][49];  // x(t) history for t-RNN (lag 2)

    const int tid = threadIdx.x;
    const int b = blockIdx.x;
    const size_t xr_base = (size_t)b * T_STEPS * 47;
    const size_t xt_base = (size_t)b * T_STEPS * 2;

    if (tid < 96) {
        in1[0][tid] = 0.0f; in1[1][tid] = 0.0f;
        if (tid >= 49) { in0[0][tid] = 0.0f; in0[1][tid] = 0.0f; }
    }

    if (tid < 384) {
        // ===== A group (waves 0-2): layer-0 step i. B group (waves 3-5): layer-1 step i-1.
        // lane (jj, q): quarter-q partial dot (24 elems) for ALL 4 gates of unit jj.
        const bool isA = (tid < 192);
        const int t0 = isA ? tid : tid - 192;
        const int jj = t0 >> 2, q = t0 & 3;
        const bool act_lane = (jj < 47);

        f2 w[4][12];
#pragma unroll
        for (int g = 0; g < 4; ++g)
#pragma unroll
            for (int u = 0; u < 12; ++u) w[g][u] = f2{0.0f, 0.0f};
        float bias = 0.0f;
        if (act_lane) {
            if (isA) {
#pragma unroll
                for (int g = 0; g < 4; ++g) {
                    const int rg = g * 47 + jj;
#pragma unroll
                    for (int u = 0; u < 12; ++u) {
                        int c0 = 24 * q + 2 * u, c1 = c0 + 1;
                        float w0 = (c0 < 49) ? rWih0[rg * 49 + c0] : rWhh0[rg * 47 + (c0 - 49)];
                        float w1 = (c1 < 49) ? rWih0[rg * 49 + c1] : rWhh0[rg * 47 + (c1 - 49)];
                        w[g][u] = f2{w0, w1};
                    }
                }
                bias = rbih0[q * 47 + jj] + rbhh0[q * 47 + jj];
            } else {
#pragma unroll
                for (int g = 0; g < 4; ++g) {
                    const int rg = g * 47 + jj;
#pragma unroll
                    for (int u = 0; u < 12; ++u) {
                        int c0 = 24 * q + 2 * u, c1 = c0 + 1;
                        float w0 = 0.0f, w1 = 0.0f;
                        if (c0 < 47) w0 = rWih1[rg * 47 + c0];
                        else if (c0 >= 48 && c0 < 95) w0 = rWhh1[rg * 47 + (c0 - 48)];
                        if (c1 < 47) w1 = rWih1[rg * 47 + c1];
                        else if (c1 >= 48 && c1 < 95) w1 = rWhh1[rg * 47 + (c1 - 48)];
                        w[g][u] = f2{w0, w1};
                    }
                }
                bias = rbih1[q * 47 + jj] + rbhh1[q * 47 + jj];
            }
        }
        // this lane activates gate q (0=i,1=f,2=g,3=o)
        const float zm = (q == 2) ? 2.0f : 1.0f;
        const float sm = (q == 2) ? 2.0f : 1.0f;
        const float sa = (q == 2) ? -1.0f : 0.0f;
        const bool wr = (q == 0) && act_lane;
        float c = 0.0f;

        __syncthreads();   // pre-loop: all init/stage writes visible

        for (int i = 0; i <= T_STEPS + 1; ++i) {
            const int cur = i & 1, nxt = cur ^ 1;
            const bool on = isA ? (i < T_STEPS) : (i >= 1 && i <= T_STEPS);
            if (on) {
                const float4* v4 = reinterpret_cast<const float4*>(isA ? in0[cur] : in1[cur]) + 6 * q;
                f2 a00 = {0,0}, a01 = {0,0}, a10 = {0,0}, a11 = {0,0};
                f2 a20 = {0,0}, a21 = {0,0}, a30 = {0,0}, a31 = {0,0};
#pragma unroll
                for (int u = 0; u < 6; ++u) {
                    float4 v = v4[u];
                    f2 lo = f2{v.x, v.y}, hi = f2{v.z, v.w};
                    a00 = __builtin_elementwise_fma(w[0][2*u],   lo, a00);
                    a01 = __builtin_elementwise_fma(w[0][2*u+1], hi, a01);
                    a10 = __builtin_elementwise_fma(w[1][2*u],   lo, a10);
                    a11 = __builtin_elementwise_fma(w[1][2*u+1], hi, a11);
                    a20 = __builtin_elementwise_fma(w[2][2*u],   lo, a20);
                    a21 = __builtin_elementwise_fma(w[2][2*u+1], hi, a21);
                    a30 = __builtin_elementwise_fma(w[3][2*u],   lo, a30);
                    a31 = __builtin_elementwise_fma(w[3][2*u+1], hi, a31);
                }
                f2 s0 = a00 + a01, s1 = a10 + a11, s2 = a20 + a21, s3 = a30 + a31;
                float P0 = s0.x + s0.y, P1 = s1.x + s1.y, P2 = s2.x + s2.y, P3 = s3.x + s3.y;
                // butterfly across the 4 quarter-lanes: full pre-acts for all 4 gates
                P0 += __shfl_xor(P0, 1, 64); P1 += __shfl_xor(P1, 1, 64);
                P2 += __shfl_xor(P2, 1, 64); P3 += __shfl_xor(P3, 1, 64);
                P0 += __shfl_xor(P0, 2, 64); P1 += __shfl_xor(P1, 2, 64);
                P2 += __shfl_xor(P2, 2, 64); P3 += __shfl_xor(P3, 2, 64);
                float pre = (q & 2) ? ((q & 1) ? P3 : P2) : ((q & 1) ? P1 : P0);
                pre += bias;
                float av = gate_act(pre, zm, sm, sa);
                // gather i,f,g,o at the q==0 lane
                float fv = __shfl_xor(av, 1, 64);
                float gv = __shfl_xor(av, 2, 64);
                float ov = __shfl_xor(av, 3, 64);
                if (wr) {
                    c = fmaf(fv, c, av * gv);
                    float h = ov * tanh_f(c);
                    if (isA) {
                        in0[nxt][49 + jj] = h;
                        in1[nxt][jj] = h;
                    } else {
                        in1[nxt][48 + jj] = h;
                        r_out[((size_t)b * T_STEPS + (i - 1)) * 47 + jj] = h;
                    }
                }
            }
            __syncthreads();
        }
    } else {
        // ===== T wave (wave 6): t-RNN step i-2 + x staging =====
        const int l = tid - 384;
        const int gt = l >> 3, p = l & 7;      // t0: 8 lanes per gate
        float wT[12];
#pragma unroll
        for (int u = 0; u < 12; ++u) wT[u] = tWih0[gt * 96 + p * 12 + u];
        const float bT0 = tbih0[gt] + tbhh0[gt];
        const float wh00 = tWhh0[gt * 2 + 0], wh01 = tWhh0[gt * 2 + 1];
        const int g1 = l & 7;                  // t1: 1 lane per gate (replicated x8)
        const float wi10 = tWih1[g1 * 2 + 0], wi11 = tWih1[g1 * 2 + 1];
        const float wh10 = tWhh1[g1 * 2 + 0], wh11 = tWhh1[g1 * 2 + 1];
        const float bT1 = tbih1[g1] + tbhh1[g1];
        const bool isg0 = ((gt >> 1) == 2);
        const float zm0 = isg0 ? 2.f : 1.f, sm0 = isg0 ? 2.f : 1.f, sa0 = isg0 ? -1.f : 0.f;
        const bool isg1 = ((g1 >> 1) == 2);
        const float zm1 = isg1 ? 2.f : 1.f, sm1 = isg1 ? 2.f : 1.f, sa1 = isg1 ? -1.f : 0.f;
        float ht00 = 0.f, ht01 = 0.f, ct00 = 0.f, ct01 = 0.f;
        float ht10 = 0.f, ht11 = 0.f, ct10 = 0.f, ct11 = 0.f;

        // depth-3 register prefetch pipeline: entering iter i, xa=x(i+1), xb=x(i+2), xc=x(i+3)
        float xa[4] = {0,0,0,0}, xb[4] = {0,0,0,0}, xc[4] = {0,0,0,0};
        if (l < 16) {
            float x0[4];
            loadx4(x0, x_r, x_t, xr_base, xt_base, l);
#pragma unroll
            for (int u = 0; u < 4; ++u) {
                int v = l + 16 * u;
                if (v < 49) { in0[0][v] = x0[u]; ring[0][v] = x0[u]; }
            }
            loadx4(xa, x_r, x_t, xr_base + 47,     xt_base + 2,     l);
            loadx4(xb, x_r, x_t, xr_base + 2 * 47, xt_base + 2 * 2, l);
            loadx4(xc, x_r, x_t, xr_base + 3 * 47, xt_base + 3 * 2, l);
        }
        __syncthreads();   // pre-loop

        for (int i = 0; i <= T_STEPS + 1; ++i) {
            const int cur = i & 1, nxt = cur ^ 1;
            if (i >= 2) {
                // t0 gates, step tau=i-2; input = [x(tau)(49) | hr1(tau)(47)]
                const float* xcr = ring[(i - 2) & 3];
                const float* h1c = in1[cur];
                float acc = 0.0f;
#pragma unroll
                for (int u = 0; u < 12; ++u) {
                    int idx = p * 12 + u;
                    const float* src = (idx < 49) ? (xcr + idx) : (h1c + (idx - 1));
                    acc = fmaf(wT[u], *src, acc);
                }
                acc += __shfl_xor(acc, 1, 64);
                acc += __shfl_xor(acc, 2, 64);
                acc += __shfl_xor(acc, 4, 64);
                float pre0 = acc + bT0 + wh00 * ht00 + wh01 * ht01;
                float act0t = gate_act(pre0, zm0, sm0, sa0);
                float iv0 = __shfl(act0t, 0, 64),  iv1 = __shfl(act0t, 8, 64);
                float fv0 = __shfl(act0t, 16, 64), fv1 = __shfl(act0t, 24, 64);
                float gv0 = __shfl(act0t, 32, 64), gv1 = __shfl(act0t, 40, 64);
                float ov0 = __shfl(act0t, 48, 64), ov1 = __shfl(act0t, 56, 64);
                ct00 = fmaf(fv0, ct00, iv0 * gv0);
                ct01 = fmaf(fv1, ct01, iv1 * gv1);
                ht00 = ov0 * tanh_f(ct00);
                ht01 = ov1 * tanh_f(ct01);
                float pre1 = bT1 + wi10 * ht00 + wi11 * ht01 + wh10 * ht10 + wh11 * ht11;
                float a1v = gate_act(pre1, zm1, sm1, sa1);
                float ji0 = __shfl(a1v, 0, 64), ji1 = __shfl(a1v, 1, 64);
                float jf0 = __shfl(a1v, 2, 64), jf1 = __shfl(a1v, 3, 64);
                float jg0 = __shfl(a1v, 4, 64), jg1 = __shfl(a1v, 5, 64);
                float jo0 = __shfl(a1v, 6, 64), jo1 = __shfl(a1v, 7, 64);
                ct10 = fmaf(jf0, ct10, ji0 * jg0);
                ct11 = fmaf(jf1, ct11, ji1 * jg1);
                ht10 = jo0 * tanh_f(ct10);
                ht11 = jo1 * tanh_f(ct11);
                if (l < 2) t_out[((size_t)b * T_STEPS + (i - 2)) * 2 + l] = (l == 0) ? ht10 : ht11;
            }
            if (l < 16) {
                const int tw = i + 1;
                if (tw < T_STEPS) {
#pragma unroll
                    for (int u = 0; u < 4; ++u) {
                        int v = l + 16 * u;
                        if (v < 49) { in0[nxt][v] = xa[u]; ring[tw & 3][v] = xa[u]; }
                    }
                }
#pragma unroll
                for (int u = 0; u < 4; ++u) { xa[u] = xb[u]; xb[u] = xc[u]; }
                int tl = i + 4;
                if (tl > T_STEPS - 1) tl = T_STEPS - 1;
                loadx4(xc, x_r, x_t, xr_base + (size_t)tl * 47, xt_base + (size_t)tl * 2, l);
            }
            __syncthreads();
        }
    }
}

extern "C" void kernel_launch(void* const* d_in, const int* in_sizes, int n_in,
                              void* d_out, int out_size, void* d_ws, size_t ws_size,
                              hipStream_t stream) {
    const float* x_r   = (const float*)d_in[0];
    const float* x_t   = (const float*)d_in[1];
    const float* rWih0 = (const float*)d_in[2];
    const float* rWhh0 = (const float*)d_in[3];
    const float* rbih0 = (const float*)d_in[4];
    const float* rbhh0 = (const float*)d_in[5];
    const float* rWih1 = (const float*)d_in[6];
    const float* rWhh1 = (const float*)d_in[7];
    const float* rbih1 = (const float*)d_in[8];
    const float* rbhh1 = (const float*)d_in[9];
    const float* tWih0 = (const float*)d_in[10];
    const float* tWhh0 = (const float*)d_in[11];
    const float* tbih0 = (const float*)d_in[12];
    const float* tbhh0 = (const float*)d_in[13];
    const float* tWih1 = (const float*)d_in[14];
    const float* tWhh1 = (const float*)d_in[15];
    const float* tbih1 = (const float*)d_in[16];
    const float* tbhh1 = (const float*)d_in[17];

    float* r_out = (float*)d_out;
    float* t_out = r_out + (size_t)256 * T_STEPS * 47;

    hipLaunchKernelGGL(adrnn_fused, dim3(256), dim3(448), 0, stream,
                       x_r, x_t, rWih0, rWhh0, rbih0, rbhh0, rWih1, rWhh1, rbih1, rbhh1,
                       tWih0, tWhh0, tbih0, tbhh0, tWih1, tWhh1, tbih1, tbhh1,
                       r_out, t_out);
}